// Round 10
// baseline (133.654 us; speedup 1.0000x reference)
//
#include <hip/hip_runtime.h>
#include <cstdint>

#define BB 4
#define LL 512
#define DD 64
#define HH 128
#define NEGV -1000000000.0f
#define NBLK 256
#define NTHR 1024
#define NACT 64   // blocks active during sinkhorn iterations (16 per batch, 32 rows each)

// ---------------------------------------------------------------------------
// Coherent (write-through / read-through) 8B accessors. Relaxed agent-scope
// atomics lower to global_load/store_dwordx2 sc0 sc1 — bypass the non-coherent
// per-XCD L2, hit the chip-coherent L3. ALL cross-block data moves through
// these, so no buffer_wbl2/buffer_inv is ever needed.
// ---------------------------------------------------------------------------
union U8 { unsigned long long u; float2 f; };

__device__ __forceinline__ float2 cload_f2(const float* p) {
    U8 v;
    v.u = __hip_atomic_load((const unsigned long long*)p,
                            __ATOMIC_RELAXED, __HIP_MEMORY_SCOPE_AGENT);
    return v.f;
}
__device__ __forceinline__ void cstore_f2(float* p, float2 x) {
    U8 v; v.f = x;
    __hip_atomic_store((unsigned long long*)p, v.u,
                       __ATOMIC_RELAXED, __HIP_MEMORY_SCOPE_AGENT);
}

// One-time flags (phase A->B handoff, B->C handoff, C->D handoff).
__device__ __forceinline__ void set_flag(unsigned* f) {
    __hip_atomic_store(f, 1u, __ATOMIC_RELAXED, __HIP_MEMORY_SCOPE_AGENT);
}
__device__ __forceinline__ void wait_flag(unsigned* f) {
    while (__hip_atomic_load(f, __ATOMIC_RELAXED, __HIP_MEMORY_SCOPE_AGENT) == 0u) {}
}

__device__ __forceinline__ float hmax4(float4 v) {
    return fmaxf(fmaxf(v.x, v.y), fmaxf(v.z, v.w));
}

// Flag word indices inside ws
#define FLG_GEMV 0        // [256] : gemv block bx done (rows bx*8..+8 of pi&pj)
#define FLG_TILE 256      // [256] : la tile (b,it8,jt) done
#define FLG_POUT 512      // [64]  : pout (b,stripe) stored

__global__ __launch_bounds__(NTHR, 4) void mega(
    const float* __restrict__ etime, const int* __restrict__ etype,
    const float* __restrict__ x, const int* __restrict__ slens,
    const float* __restrict__ gum, const float* __restrict__ W1,
    const float* __restrict__ b1, const float* __restrict__ W2,
    const float* __restrict__ b2, float* __restrict__ out, float* __restrict__ ws)
{
    // LDS map (floats):
    //   [0,16384)      phaseB: sp(8192)+sq(8192); then cbuf(16384); phaseC: sla 32x512
    //   [16384,17408)  redm [2][512] (epilogue column sums)
    //   [17408,18432)  reds [2][512]
    //   [18432,18944)  clse [512]
    //   [18944,19072)  sw2  [128]
    __shared__ float smem[19072];

    unsigned* flg = (unsigned*)ws;
    // Sinkhorn partials: [2 slots][B][16 stripes][512 cols] x (m, signed s).
    // The STORE is the signal: s >= 1 always (stripe max contributes exp(0)=1),
    // stored as +s on (it>>1)&1==0, -s on ==1; slot = it&1. A (slot,sign) pair
    // recurs every 4 iterations, far beyond the <=2-iteration inter-block skew
    // the dependency chain allows. Region memset to 0 every replay.
    float* cpkG  = ws + 2048;                      // 131072 floats (512 KB)
    float* piG   = cpkG + 2 * BB * 16 * LL * 2;    // [2048][128]
    float* pjG   = piG + BB * LL * HH;             // [2048][128]
    float* laG   = pjG + BB * LL * HH;             // [4][512][512]
    float* poutG = laG + (size_t)BB * LL * LL;     // [4][16][512] x (ty,tm)

    const int t = threadIdx.x;
    const int bx = blockIdx.x;

    // ============== Phase A: GEMV — block bx computes rows bx*8..+8 ===========
    {
        int arr = t >> 9;                  // 0: pi, 1: pj
        int row = (t >> 6) & 7;            // 0..7
        int h0  = (t & 63) << 1;
        int grow = (bx << 3) + row;        // global row 0..2047
        const float* xr = x + (size_t)grow * DD;
        const float* wb = W1 + (size_t)(arr * DD) * HH + h0;
        float a0 = arr ? 0.f : b1[h0];
        float a1 = arr ? 0.f : b1[h0 + 1];
        #pragma unroll 8
        for (int d = 0; d < DD; ++d) {
            float xv = xr[d];
            float2 w = *(const float2*)(wb + d * HH);
            a0 = fmaf(xv, w.x, a0);
            a1 = fmaf(xv, w.y, a1);
        }
        cstore_f2((arr ? pjG : piG) + (size_t)grow * HH + h0, make_float2(a0, a1));
        __builtin_amdgcn_fence(__ATOMIC_RELEASE, "workgroup");
        __syncthreads();
        if (t == 0) set_flag(flg + FLG_GEMV + bx);
    }

    // ============== Phase B: scores -> la0 (masked, /tau) ======================
    {
        float* sp  = smem;
        float* sq  = smem + 8192;
        float* sw2 = smem + 18944;
        int jt = bx & 7, it8 = (bx >> 3) & 7, b = bx >> 6;
        int i0 = it8 << 6, j0 = jt << 6;
        int rowb = b * LL + i0, colb = b * LL + j0;

        if (t < 8)              wait_flag(flg + FLG_GEMV + (b << 6) + (it8 << 3) + t);
        else if (t < 16)        wait_flag(flg + FLG_GEMV + (b << 6) + (jt << 3) + (t - 8));
        if (t < HH) sw2[t] = W2[t];
        __syncthreads();

        // stage pi/pj tiles (coherent 8B loads), XOR-swizzled into LDS
        #pragma unroll
        for (int k = 0; k < 8; ++k) {
            int idx = (k << 10) + t;        // 0..8191 8B units
            int buf = idx >> 12;            // 0: pi->sp, 1: pj->sq
            int u   = idx & 4095;
            int row = u >> 6;               // 0..63
            int du  = u & 63;               // h0 = du*2
            int q   = du >> 1;
            int hi  = du & 1;
            int dq  = q ^ ((row >> 2) & 7);
            const float* src = (buf ? pjG + (size_t)(colb + row) * HH
                                    : piG + (size_t)(rowb + row) * HH) + (du << 1);
            float2 v = cload_f2(src);
            float* dst = (buf ? sq : sp) + row * HH + (dq << 2) + (hi << 1);
            *(float2*)dst = v;
        }
        __syncthreads();

        // GEMM: h split into 4 groups of 8 hq; 256-thread group does 4x4 tile
        int hg = t >> 8, tt = t & 255;
        int w = tt >> 6, lane = tt & 63;
        int ti = ((w >> 1) << 3) + (lane >> 3);
        int tj = ((w & 1) << 3) + (lane & 7);
        int kti = ti & 7, ktj = tj & 7;

        float acc[4][4];
        #pragma unroll
        for (int a = 0; a < 4; ++a)
            #pragma unroll
            for (int c = 0; c < 4; ++c) acc[a][c] = 0.f;

        for (int hq = hg * 8; hq < hg * 8 + 8; ++hq) {
            float4 w4 = *(const float4*)(sw2 + (hq << 2));
            int offi = (hq ^ kti) << 2;
            int offj = (hq ^ ktj) << 2;
            float4 pa[4], pb[4];
            #pragma unroll
            for (int a = 0; a < 4; ++a) pa[a] = *(const float4*)(sp + (4*ti + a) * HH + offi);
            #pragma unroll
            for (int c = 0; c < 4; ++c) pb[c] = *(const float4*)(sq + (4*tj + c) * HH + offj);
            #pragma unroll
            for (int a = 0; a < 4; ++a) {
                #pragma unroll
                for (int c = 0; c < 4; ++c) {
                    float t0 = fmaxf(pa[a].x + pb[c].x, 0.f);
                    float t1 = fmaxf(pa[a].y + pb[c].y, 0.f);
                    float t2 = fmaxf(pa[a].z + pb[c].z, 0.f);
                    float t3 = fmaxf(pa[a].w + pb[c].w, 0.f);
                    float s = acc[a][c];
                    s += t0 * w4.x; s += t1 * w4.y; s += t2 * w4.z; s += t3 * w4.w;
                    acc[a][c] = s;
                }
            }
        }
        __syncthreads();                      // done with sp/sq
        float* cbuf = smem;                   // alias: [4 groups][256 tt][16]
        #pragma unroll
        for (int a = 0; a < 4; ++a)
            #pragma unroll
            for (int c = 0; c < 4; ++c)
                cbuf[(((hg << 8) + tt) << 4) + (a << 2) + c] = acc[a][c];
        __syncthreads();

        int tt2 = t >> 2, a2 = t & 3;
        int w2_ = tt2 >> 6, lane2 = tt2 & 63;
        int ti2 = ((w2_ >> 1) << 3) + (lane2 >> 3);
        int tj2 = ((w2_ & 1) << 3) + (lane2 & 7);
        float4 o = make_float4(0.f, 0.f, 0.f, 0.f);
        #pragma unroll
        for (int g = 0; g < 4; ++g) {
            float4 pp = *(const float4*)(cbuf + (((g << 8) + tt2) << 4) + (a2 << 2));
            o.x += pp.x; o.y += pp.y; o.z += pp.z; o.w += pp.w;
        }
        int sl = slens[b];
        float bb2 = b2[0];
        int ig = i0 + 4 * ti2 + a2;
        int jb = j0 + 4 * tj2;
        float4 g4 = *(const float4*)(gum + ((size_t)(b * LL + ig)) * LL + jb);
        bool iv = ig < sl;
        float4 res;
        res.x = (iv && (jb + 0) < sl) ? (o.x + bb2 + g4.x) * 2.0f : NEGV;
        res.y = (iv && (jb + 1) < sl) ? (o.y + bb2 + g4.y) * 2.0f : NEGV;
        res.z = (iv && (jb + 2) < sl) ? (o.z + bb2 + g4.z) * 2.0f : NEGV;
        res.w = (iv && (jb + 3) < sl) ? (o.w + bb2 + g4.w) * 2.0f : NEGV;
        float* lap = laG + ((size_t)(b * LL + ig)) * LL + jb;
        cstore_f2(lap,     make_float2(res.x, res.y));
        cstore_f2(lap + 2, make_float2(res.z, res.w));
        __builtin_amdgcn_fence(__ATOMIC_RELEASE, "workgroup");
        __syncthreads();
        if (t == 0) set_flag(flg + FLG_TILE + (b << 6) + (it8 << 3) + jt);
    }

    // ===================== Phase C: 10 Sinkhorn iterations =====================
    if (bx >= NACT) return;

    const int b2i = bx >> 4;
    const int stripe = bx & 15;
    const int r0 = stripe << 5;               // 32 rows per active block
    float* sla  = smem;                       // [32][512] row-normed R (UNMASKED)
    float* redm = smem + 16384;               // [2][512] (epilogue)
    float* reds = smem + 17408;               // [2][512] (epilogue)
    float* clse = smem + 18432;               // [512] current col-LSE
    const int sl_a = slens[b2i];
    float tyv = 0.f, tmv = 0.f;

    {
        // need the 8 la tiles of this stripe's row band (it8 = stripe>>1)
        if (t < 8) wait_flag(flg + FLG_TILE + (b2i << 6) + ((stripe >> 1) << 3) + t);
        __syncthreads();
        const float* src = laG + (((size_t)(b2i << 9) + r0) << 9);
        #pragma unroll
        for (int k = 0; k < 8; ++k) {
            int u = (k << 10) + t;             // 8192 8B units = 32x512 floats
            float2 v = cload_f2(src + (u << 1));
            *(float2*)(sla + (u << 1)) = v;
        }
        if (t < 512) clse[t] = 0.f;            // iter-0: subtract nothing
        __syncthreads();
    }

    for (int it = 0; it < 10; ++it) {
        const int last = (it == 9);
        const int slot = it & 1;
        const bool neg = (it >> 1) & 1;        // sign encoding for slot reuse

        // ---- fused row pass: read (mask ? NEG : R - clse), LSE, write R' ------
        {
            int r = t >> 5, cq = t & 31;
            int grow = r0 + r;
            bool ivR = grow < sl_a;
            float4 v[4];
            #pragma unroll
            for (int k = 0; k < 4; ++k) {
                int cb = (cq + (k << 5)) << 2;
                float4 a = *(float4*)(sla + (r << 9) + cb);
                float4 l = *(const float4*)(clse + cb);
                v[k].x = (ivR && (cb + 0) < sl_a) ? a.x - l.x : NEGV;
                v[k].y = (ivR && (cb + 1) < sl_a) ? a.y - l.y : NEGV;
                v[k].z = (ivR && (cb + 2) < sl_a) ? a.z - l.z : NEGV;
                v[k].w = (ivR && (cb + 3) < sl_a) ? a.w - l.w : NEGV;
            }
            float m = fmaxf(fmaxf(hmax4(v[0]), hmax4(v[1])), fmaxf(hmax4(v[2]), hmax4(v[3])));
            #pragma unroll
            for (int off = 16; off; off >>= 1) m = fmaxf(m, __shfl_xor(m, off));
            float s = 0.f;
            #pragma unroll
            for (int k = 0; k < 4; ++k)
                s += __expf(v[k].x - m) + __expf(v[k].y - m) + __expf(v[k].z - m) + __expf(v[k].w - m);
            #pragma unroll
            for (int off = 16; off; off >>= 1) s += __shfl_xor(s, off);
            float lse = m + __logf(s);        // NEG-absorption preserved in fp32
            #pragma unroll
            for (int k = 0; k < 4; ++k) {
                v[k].x -= lse; v[k].y -= lse; v[k].z -= lse; v[k].w -= lse;
                *(float4*)(sla + (r << 9) + ((cq + (k << 5)) << 2)) = v[k];
            }
        }
        __syncthreads();                                               // S1

        // ---- column partial over this block's 32 rows (t<512, col t), store --
        // The 8B atomic store IS the inter-block signal (s >= 1 always).
        if (t < 512) {
            float mp = sla[t];
            #pragma unroll
            for (int rr = 1; rr < 32; ++rr) mp = fmaxf(mp, sla[(rr << 9) + t]);
            float spv = 0.f;
            #pragma unroll
            for (int rr = 0; rr < 32; ++rr) spv += __expf(sla[(rr << 9) + t] - mp);
            cstore_f2(cpkG + ((size_t)(((slot * BB + b2i) << 4) + stripe) * LL + t) * 2,
                      make_float2(mp, neg ? -spv : spv));

            // ---- poll + combine the 16 stripes' partials for column t --------
            const float* pB = cpkG + (size_t)(((slot * BB + b2i) << 4) * LL) * 2;
            float mreg[16], sreg[16];
            #pragma unroll
            for (int g = 0; g < 16; ++g) {
                float2 ms = cload_f2(pB + ((size_t)(g * LL + t)) * 2);
                mreg[g] = ms.x; sreg[g] = ms.y;
            }
            while (true) {
                bool ok = true;
                #pragma unroll
                for (int g = 0; g < 16; ++g)
                    ok &= neg ? (sreg[g] < 0.f) : (sreg[g] > 0.f);
                if (ok) break;
                #pragma unroll
                for (int g = 0; g < 16; ++g) {
                    bool good = neg ? (sreg[g] < 0.f) : (sreg[g] > 0.f);
                    if (!good) {
                        float2 ms = cload_f2(pB + ((size_t)(g * LL + t)) * 2);
                        mreg[g] = ms.x; sreg[g] = ms.y;
                    }
                }
            }
            float M = mreg[0];
            #pragma unroll
            for (int g = 1; g < 16; ++g) M = fmaxf(M, mreg[g]);
            float S = 0.f;
            #pragma unroll
            for (int g = 0; g < 16; ++g)
                S = fmaf(fabsf(sreg[g]), __expf(mreg[g] - M), S);
            clse[t] = M + __logf(S);
        }
        __syncthreads();                                               // S2

        if (last) {
            // final: perm = mask ? 0 : exp(R - clse); fused column sums
            int r = t >> 5, cq = t & 31;
            int grow = r0 + r;
            bool ivR = grow < sl_a;
            float etf = (float)etype[(b2i << 9) + grow];
            float etv = etime[(b2i << 9) + grow];
            float4 p[4];
            #pragma unroll
            for (int k = 0; k < 4; ++k) {
                int cb = (cq + (k << 5)) << 2;
                float4 v = *(float4*)(sla + (r << 9) + cb);
                float4 l = *(const float4*)(clse + cb);
                float4 q;
                q.x = (ivR && (cb + 0) < sl_a) ? __expf(v.x - l.x) : 0.f;
                q.y = (ivR && (cb + 1) < sl_a) ? __expf(v.y - l.y) : 0.f;
                q.z = (ivR && (cb + 2) < sl_a) ? __expf(v.z - l.z) : 0.f;
                q.w = (ivR && (cb + 3) < sl_a) ? __expf(v.w - l.w) : 0.f;
                p[k] = q;
                *(float4*)(out + 2 * BB * LL + (((size_t)(b2i << 9) + grow) << 9) + cb) = q;
            }
            // type-weighted column partial (transpose via sla)
            #pragma unroll
            for (int k = 0; k < 4; ++k) {
                int cb = (cq + (k << 5)) << 2;
                *(float4*)(sla + (r << 9) + cb) =
                    make_float4(p[k].x * etf, p[k].y * etf, p[k].z * etf, p[k].w * etf);
            }
            __syncthreads();
            {
                int c2 = t & 511, h2 = t >> 9;
                float sA = 0.f;
                #pragma unroll
                for (int rr = 0; rr < 16; ++rr) sA += sla[(((h2 << 4) + rr) << 9) + c2];
                redm[(h2 << 9) + c2] = sA;
            }
            __syncthreads();
            if (t < 512) tyv = redm[t] + redm[512 + t];
            __syncthreads();
            // time-weighted column partial
            #pragma unroll
            for (int k = 0; k < 4; ++k) {
                int cb = (cq + (k << 5)) << 2;
                *(float4*)(sla + (r << 9) + cb) =
                    make_float4(p[k].x * etv, p[k].y * etv, p[k].z * etv, p[k].w * etv);
            }
            __syncthreads();
            {
                int c2 = t & 511, h2 = t >> 9;
                float sB = 0.f;
                #pragma unroll
                for (int rr = 0; rr < 16; ++rr) sB += sla[(((h2 << 4) + rr) << 9) + c2];
                reds[(h2 << 9) + c2] = sB;
            }
            __syncthreads();
            if (t < 512) {
                tmv = reds[t] + reds[512 + t];
                cstore_f2(poutG + (size_t)(((b2i << 4) + stripe) * LL + t) * 2,
                          make_float2(tyv, tmv));
            }
            __builtin_amdgcn_fence(__ATOMIC_RELEASE, "workgroup");
            __syncthreads();
            if (t == 0) set_flag(flg + FLG_POUT + (b2i << 4) + stripe);
        }
    }

    // ===================== Phase D: combine output partials (per batch) ========
    if (t < 16) wait_flag(flg + FLG_POUT + (b2i << 4) + t);
    __syncthreads();
    if (t < 32) {
        int c = (stripe << 5) + t;
        float a = 0.f, d = 0.f;
        #pragma unroll
        for (int s = 0; s < 16; ++s) {
            float2 p = cload_f2(poutG + (size_t)(((b2i << 4) + s) * LL + c) * 2);
            a += p.x; d += p.y;
        }
        out[(b2i << 9) + c] = a;                 // types_permed
        out[BB * LL + (b2i << 9) + c] = d;       // times_permed
    }
}

extern "C" void kernel_launch(void* const* d_in, const int* in_sizes, int n_in,
                              void* d_out, int out_size, void* d_ws, size_t ws_size,
                              hipStream_t stream)
{
    const float* etime = (const float*)d_in[0];
    const int*   etype = (const int*)d_in[1];
    const float* x     = (const float*)d_in[2];
    const int*   slens = (const int*)d_in[3];
    const float* gum   = (const float*)d_in[4];
    const float* W1    = (const float*)d_in[5];
    const float* b1    = (const float*)d_in[6];
    const float* W2    = (const float*)d_in[7];
    const float* b2    = (const float*)d_in[8];
    float* out = (float*)d_out;
    float* wsf = (float*)d_ws;

    // zero flags (8 KB) + sinkhorn partial region (512 KB) every replay:
    // the partial stores double as sync signals, so stale nonzero values from
    // a previous replay must be cleared. ~0.1 us at fill BW.
    hipMemsetAsync(d_ws, 0, 8192 + 2 * BB * 16 * LL * 2 * sizeof(float), stream);

    void* args[] = {(void*)&etime, (void*)&etype, (void*)&x, (void*)&slens, (void*)&gum,
                    (void*)&W1, (void*)&b1, (void*)&W2, (void*)&b2, (void*)&out, (void*)&wsf};
    hipError_t err = hipLaunchCooperativeKernel((const void*)mega, dim3(NBLK), dim3(NTHR),
                                                args, 0, stream);
    if (err != hipSuccess) {
        // 256 blocks x 1024 thr, ~76KB LDS -> 1 block/CU on 256 CUs (co-resident;
        // flag/partial deps only ever point at co-resident blocks).
        mega<<<NBLK, NTHR, 0, stream>>>(etime, etype, x, slens, gum, W1, b1, W2, b2, out, wsf);
    }
}

// Round 11
// 112.397 us; speedup vs baseline: 1.1891x; 1.1891x over previous
//
#include <hip/hip_runtime.h>
#include <cstdint>

#define BB 4
#define LL 512
#define DD 64
#define HH 128
#define NEGV -1000000000.0f
#define NBLK 256
#define NTHR 1024
#define NACT 64   // blocks active during sinkhorn iterations (16 per batch, 32 rows each)

// ---------------------------------------------------------------------------
// Coherent (write-through / read-through) 8B accessors. Relaxed agent-scope
// atomics lower to global_load/store_dwordx2 sc0 sc1 — bypass the non-coherent
// per-XCD L2, hit the chip-coherent L3. ALL cross-block data moves through
// these, so no buffer_wbl2/buffer_inv is ever needed.
// ---------------------------------------------------------------------------
union U8 { unsigned long long u; float2 f; };

__device__ __forceinline__ float2 cload_f2(const float* p) {
    U8 v;
    v.u = __hip_atomic_load((const unsigned long long*)p,
                            __ATOMIC_RELAXED, __HIP_MEMORY_SCOPE_AGENT);
    return v.f;
}
__device__ __forceinline__ void cstore_f2(float* p, float2 x) {
    U8 v; v.f = x;
    __hip_atomic_store((unsigned long long*)p, v.u,
                       __ATOMIC_RELAXED, __HIP_MEMORY_SCOPE_AGENT);
}

// Point-to-point flag sync: writer does data cstores -> fence(release,
// workgroup) [per-wave vmcnt drain; sc1 store ack = visible at L3] ->
// __syncthreads -> set_flag. Reader: NARROW fan-in — 16 threads poll 16
// adjacent flag words (one 64B L3 line), then __syncthreads hands visibility
// to the block. (Round-10 lesson: wide per-datum polling with divergent
// retries contends with the writers and regresses ~25%.)
__device__ __forceinline__ void set_flag(unsigned* f) {
    __hip_atomic_store(f, 1u, __ATOMIC_RELAXED, __HIP_MEMORY_SCOPE_AGENT);
}
__device__ __forceinline__ void wait_flag(unsigned* f) {
    while (__hip_atomic_load(f, __ATOMIC_RELAXED, __HIP_MEMORY_SCOPE_AGENT) == 0u) {}
}

__device__ __forceinline__ float hmax4(float4 v) {
    return fmaxf(fmaxf(v.x, v.y), fmaxf(v.z, v.w));
}

// Flag word indices inside ws (all < 2048; memset 8192 B per replay)
#define FLG_GEMV 0        // [256] : gemv block bx done (rows bx*8..+8 of pi&pj)
#define FLG_TILE 256      // [256] : la tile (b,it8,jt) done
#define FLG_ITER 512      // [640] : iter partial (b,it,stripe) stored
#define FLG_POUT 1152     // [64]  : pout (b,stripe) stored

__global__ __launch_bounds__(NTHR, 4) void mega(
    const float* __restrict__ etime, const int* __restrict__ etype,
    const float* __restrict__ x, const int* __restrict__ slens,
    const float* __restrict__ gum, const float* __restrict__ W1,
    const float* __restrict__ b1, const float* __restrict__ W2,
    const float* __restrict__ b2, float* __restrict__ out, float* __restrict__ ws)
{
    // LDS map (floats):
    //   [0,16384)      phaseB: sp(8192)+sq(8192); then cbuf(16384); phaseC: sla 32x512
    //   [16384,17408)  redm [2][512] (epilogue column sums)
    //   [17408,18432)  reds [2][512] (epilogue)
    //   [18432,18944)  clse [512]
    //   [18944,19072)  sw2  [128]
    __shared__ float smem[19072];

    unsigned* flg = (unsigned*)ws;
    float* piG   = ws + 2048;                      // [2048][128]
    float* pjG   = piG + BB * LL * HH;             // [2048][128]
    float* laG   = pjG + BB * LL * HH;             // [4][512][512]
    float* cpkG  = laG + (size_t)BB * LL * LL;     // [2 slots][4][16][512] x (m,s)
    float* poutG = cpkG + (size_t)2 * BB * 16 * LL * 2; // [4][16][512] x (ty,tm)

    const int t = threadIdx.x;
    const int bx = blockIdx.x;

    // ============== Phase A: GEMV — block bx computes rows bx*8..+8 ===========
    {
        int arr = t >> 9;                  // 0: pi, 1: pj
        int row = (t >> 6) & 7;            // 0..7
        int h0  = (t & 63) << 1;
        int grow = (bx << 3) + row;        // global row 0..2047
        const float* xr = x + (size_t)grow * DD;
        const float* wb = W1 + (size_t)(arr * DD) * HH + h0;
        float a0 = arr ? 0.f : b1[h0];
        float a1 = arr ? 0.f : b1[h0 + 1];
        #pragma unroll 8
        for (int d = 0; d < DD; ++d) {
            float xv = xr[d];
            float2 w = *(const float2*)(wb + d * HH);
            a0 = fmaf(xv, w.x, a0);
            a1 = fmaf(xv, w.y, a1);
        }
        cstore_f2((arr ? pjG : piG) + (size_t)grow * HH + h0, make_float2(a0, a1));
        __builtin_amdgcn_fence(__ATOMIC_RELEASE, "workgroup");
        __syncthreads();
        if (t == 0) set_flag(flg + FLG_GEMV + bx);
    }

    // ============== Phase B: scores -> la0 (masked, /tau) ======================
    {
        float* sp  = smem;
        float* sq  = smem + 8192;
        float* sw2 = smem + 18944;
        int jt = bx & 7, it8 = (bx >> 3) & 7, b = bx >> 6;
        int i0 = it8 << 6, j0 = jt << 6;
        int rowb = b * LL + i0, colb = b * LL + j0;

        if (t < 8)              wait_flag(flg + FLG_GEMV + (b << 6) + (it8 << 3) + t);
        else if (t < 16)        wait_flag(flg + FLG_GEMV + (b << 6) + (jt << 3) + (t - 8));
        if (t < HH) sw2[t] = W2[t];
        __syncthreads();

        // stage pi/pj tiles (coherent 8B loads), XOR-swizzled into LDS
        #pragma unroll
        for (int k = 0; k < 8; ++k) {
            int idx = (k << 10) + t;        // 0..8191 8B units
            int buf = idx >> 12;            // 0: pi->sp, 1: pj->sq
            int u   = idx & 4095;
            int row = u >> 6;               // 0..63
            int du  = u & 63;               // h0 = du*2
            int q   = du >> 1;
            int hi  = du & 1;
            int dq  = q ^ ((row >> 2) & 7);
            const float* src = (buf ? pjG + (size_t)(colb + row) * HH
                                    : piG + (size_t)(rowb + row) * HH) + (du << 1);
            float2 v = cload_f2(src);
            float* dst = (buf ? sq : sp) + row * HH + (dq << 2) + (hi << 1);
            *(float2*)dst = v;
        }
        __syncthreads();

        // GEMM: h split into 4 groups of 8 hq; 256-thread group does 4x4 tile
        int hg = t >> 8, tt = t & 255;
        int w = tt >> 6, lane = tt & 63;
        int ti = ((w >> 1) << 3) + (lane >> 3);
        int tj = ((w & 1) << 3) + (lane & 7);
        int kti = ti & 7, ktj = tj & 7;

        float acc[4][4];
        #pragma unroll
        for (int a = 0; a < 4; ++a)
            #pragma unroll
            for (int c = 0; c < 4; ++c) acc[a][c] = 0.f;

        for (int hq = hg * 8; hq < hg * 8 + 8; ++hq) {
            float4 w4 = *(const float4*)(sw2 + (hq << 2));
            int offi = (hq ^ kti) << 2;
            int offj = (hq ^ ktj) << 2;
            float4 pa[4], pb[4];
            #pragma unroll
            for (int a = 0; a < 4; ++a) pa[a] = *(const float4*)(sp + (4*ti + a) * HH + offi);
            #pragma unroll
            for (int c = 0; c < 4; ++c) pb[c] = *(const float4*)(sq + (4*tj + c) * HH + offj);
            #pragma unroll
            for (int a = 0; a < 4; ++a) {
                #pragma unroll
                for (int c = 0; c < 4; ++c) {
                    float t0 = fmaxf(pa[a].x + pb[c].x, 0.f);
                    float t1 = fmaxf(pa[a].y + pb[c].y, 0.f);
                    float t2 = fmaxf(pa[a].z + pb[c].z, 0.f);
                    float t3 = fmaxf(pa[a].w + pb[c].w, 0.f);
                    float s = acc[a][c];
                    s += t0 * w4.x; s += t1 * w4.y; s += t2 * w4.z; s += t3 * w4.w;
                    acc[a][c] = s;
                }
            }
        }
        __syncthreads();                      // done with sp/sq
        float* cbuf = smem;                   // alias: [4 groups][256 tt][16]
        #pragma unroll
        for (int a = 0; a < 4; ++a)
            #pragma unroll
            for (int c = 0; c < 4; ++c)
                cbuf[(((hg << 8) + tt) << 4) + (a << 2) + c] = acc[a][c];
        __syncthreads();

        int tt2 = t >> 2, a2 = t & 3;
        int w2_ = tt2 >> 6, lane2 = tt2 & 63;
        int ti2 = ((w2_ >> 1) << 3) + (lane2 >> 3);
        int tj2 = ((w2_ & 1) << 3) + (lane2 & 7);
        float4 o = make_float4(0.f, 0.f, 0.f, 0.f);
        #pragma unroll
        for (int g = 0; g < 4; ++g) {
            float4 pp = *(const float4*)(cbuf + (((g << 8) + tt2) << 4) + (a2 << 2));
            o.x += pp.x; o.y += pp.y; o.z += pp.z; o.w += pp.w;
        }
        int sl = slens[b];
        float bb2 = b2[0];
        int ig = i0 + 4 * ti2 + a2;
        int jb = j0 + 4 * tj2;
        float4 g4 = *(const float4*)(gum + ((size_t)(b * LL + ig)) * LL + jb);
        bool iv = ig < sl;
        float4 res;
        res.x = (iv && (jb + 0) < sl) ? (o.x + bb2 + g4.x) * 2.0f : NEGV;
        res.y = (iv && (jb + 1) < sl) ? (o.y + bb2 + g4.y) * 2.0f : NEGV;
        res.z = (iv && (jb + 2) < sl) ? (o.z + bb2 + g4.z) * 2.0f : NEGV;
        res.w = (iv && (jb + 3) < sl) ? (o.w + bb2 + g4.w) * 2.0f : NEGV;
        float* lap = laG + ((size_t)(b * LL + ig)) * LL + jb;
        cstore_f2(lap,     make_float2(res.x, res.y));
        cstore_f2(lap + 2, make_float2(res.z, res.w));
        __builtin_amdgcn_fence(__ATOMIC_RELEASE, "workgroup");
        __syncthreads();
        if (t == 0) set_flag(flg + FLG_TILE + (b << 6) + (it8 << 3) + jt);
    }

    // ===================== Phase C: 10 Sinkhorn iterations =====================
    if (bx >= NACT) return;

    const int b2i = bx >> 4;
    const int stripe = bx & 15;
    const int r0 = stripe << 5;               // 32 rows per active block
    float* sla  = smem;                       // [32][512] row-normed R (UNMASKED)
    float* redm = smem + 16384;               // [2][512] (epilogue)
    float* reds = smem + 17408;               // [2][512] (epilogue)
    float* clse = smem + 18432;               // [512] current col-LSE
    const int sl_a = slens[b2i];
    float tyv = 0.f, tmv = 0.f;

    {
        // need the 8 la tiles of this stripe's row band (it8 = stripe>>1)
        if (t < 8) wait_flag(flg + FLG_TILE + (b2i << 6) + ((stripe >> 1) << 3) + t);
        __syncthreads();
        const float* src = laG + (((size_t)(b2i << 9) + r0) << 9);
        #pragma unroll
        for (int k = 0; k < 8; ++k) {
            int u = (k << 10) + t;             // 8192 8B units = 32x512 floats
            float2 v = cload_f2(src + (u << 1));
            *(float2*)(sla + (u << 1)) = v;
        }
        if (t < 512) clse[t] = 0.f;            // iter-0: subtract nothing
        __syncthreads();
    }

    for (int it = 0; it < 10; ++it) {
        const int last = (it == 9);
        const int slot = it & 1;               // 2 cpk slots; safe: per-iter flags
                                               // bound inter-block skew < 2 iters

        // ---- fused row pass: read (mask ? NEG : R - clse), LSE, write R' ------
        {
            int r = t >> 5, cq = t & 31;
            int grow = r0 + r;
            bool ivR = grow < sl_a;
            float4 v[4];
            #pragma unroll
            for (int k = 0; k < 4; ++k) {
                int cb = (cq + (k << 5)) << 2;
                float4 a = *(float4*)(sla + (r << 9) + cb);
                float4 l = *(const float4*)(clse + cb);
                v[k].x = (ivR && (cb + 0) < sl_a) ? a.x - l.x : NEGV;
                v[k].y = (ivR && (cb + 1) < sl_a) ? a.y - l.y : NEGV;
                v[k].z = (ivR && (cb + 2) < sl_a) ? a.z - l.z : NEGV;
                v[k].w = (ivR && (cb + 3) < sl_a) ? a.w - l.w : NEGV;
            }
            float m = fmaxf(fmaxf(hmax4(v[0]), hmax4(v[1])), fmaxf(hmax4(v[2]), hmax4(v[3])));
            #pragma unroll
            for (int off = 16; off; off >>= 1) m = fmaxf(m, __shfl_xor(m, off));
            float s = 0.f;
            #pragma unroll
            for (int k = 0; k < 4; ++k)
                s += __expf(v[k].x - m) + __expf(v[k].y - m) + __expf(v[k].z - m) + __expf(v[k].w - m);
            #pragma unroll
            for (int off = 16; off; off >>= 1) s += __shfl_xor(s, off);
            float lse = m + __logf(s);        // NEG-absorption preserved in fp32
            #pragma unroll
            for (int k = 0; k < 4; ++k) {
                v[k].x -= lse; v[k].y -= lse; v[k].z -= lse; v[k].w -= lse;
                *(float4*)(sla + (r << 9) + ((cq + (k << 5)) << 2)) = v[k];
            }
        }
        __syncthreads();                                               // S1

        // ---- direct column partial over this block's 32 rows (t<512) ---------
        // (replaces the two-half redm/reds pre-combine: one fewer sync + one
        //  fewer LDS round-trip; numerics validated in round 10, absmax same)
        if (t < 512) {
            float mp = sla[t];
            #pragma unroll
            for (int rr = 1; rr < 32; ++rr) mp = fmaxf(mp, sla[(rr << 9) + t]);
            float spv = 0.f;
            #pragma unroll
            for (int rr = 0; rr < 32; ++rr) spv += __expf(sla[(rr << 9) + t] - mp);
            cstore_f2(cpkG + ((size_t)(((slot * BB + b2i) << 4) + stripe) * LL + t) * 2,
                      make_float2(mp, spv));
        }
        __builtin_amdgcn_fence(__ATOMIC_RELEASE, "workgroup");
        __syncthreads();                                               // S2
        if (t == 0) set_flag(flg + FLG_ITER + (((b2i * 10) + it) << 4) + stripe);
        if (t < 16) wait_flag(flg + FLG_ITER + (((b2i * 10) + it) << 4) + t);
        __syncthreads();                                               // S3

        // ---- flat combine: 512 threads each read all 16 (m,s) partials -------
        if (t < 512) {
            const float* pB = cpkG + (size_t)(((slot * BB + b2i) << 4) * LL) * 2;
            float mreg[16], sreg[16];
            #pragma unroll
            for (int g = 0; g < 16; ++g) {
                float2 ms = cload_f2(pB + (size_t)(g * LL + t) * 2);
                mreg[g] = ms.x; sreg[g] = ms.y;
            }
            float M = mreg[0];
            #pragma unroll
            for (int g = 1; g < 16; ++g) M = fmaxf(M, mreg[g]);
            float S = 0.f;
            #pragma unroll
            for (int g = 0; g < 16; ++g)
                S = fmaf(sreg[g], __expf(mreg[g] - M), S);
            clse[t] = M + __logf(S);
        }
        __syncthreads();                                               // S4

        if (last) {
            // final: perm = mask ? 0 : exp(R - clse); fused column sums
            int r = t >> 5, cq = t & 31;
            int grow = r0 + r;
            bool ivR = grow < sl_a;
            float etf = (float)etype[(b2i << 9) + grow];
            float etv = etime[(b2i << 9) + grow];
            float4 p[4];
            #pragma unroll
            for (int k = 0; k < 4; ++k) {
                int cb = (cq + (k << 5)) << 2;
                float4 v = *(float4*)(sla + (r << 9) + cb);
                float4 l = *(const float4*)(clse + cb);
                float4 q;
                q.x = (ivR && (cb + 0) < sl_a) ? __expf(v.x - l.x) : 0.f;
                q.y = (ivR && (cb + 1) < sl_a) ? __expf(v.y - l.y) : 0.f;
                q.z = (ivR && (cb + 2) < sl_a) ? __expf(v.z - l.z) : 0.f;
                q.w = (ivR && (cb + 3) < sl_a) ? __expf(v.w - l.w) : 0.f;
                p[k] = q;
                *(float4*)(out + 2 * BB * LL + (((size_t)(b2i << 9) + grow) << 9) + cb) = q;
            }
            // type-weighted column partial (transpose via sla)
            #pragma unroll
            for (int k = 0; k < 4; ++k) {
                int cb = (cq + (k << 5)) << 2;
                *(float4*)(sla + (r << 9) + cb) =
                    make_float4(p[k].x * etf, p[k].y * etf, p[k].z * etf, p[k].w * etf);
            }
            __syncthreads();
            {
                int c2 = t & 511, h2 = t >> 9;
                float sA = 0.f;
                #pragma unroll
                for (int rr = 0; rr < 16; ++rr) sA += sla[(((h2 << 4) + rr) << 9) + c2];
                redm[(h2 << 9) + c2] = sA;
            }
            __syncthreads();
            if (t < 512) tyv = redm[t] + redm[512 + t];
            __syncthreads();
            // time-weighted column partial
            #pragma unroll
            for (int k = 0; k < 4; ++k) {
                int cb = (cq + (k << 5)) << 2;
                *(float4*)(sla + (r << 9) + cb) =
                    make_float4(p[k].x * etv, p[k].y * etv, p[k].z * etv, p[k].w * etv);
            }
            __syncthreads();
            {
                int c2 = t & 511, h2 = t >> 9;
                float sB = 0.f;
                #pragma unroll
                for (int rr = 0; rr < 16; ++rr) sB += sla[(((h2 << 4) + rr) << 9) + c2];
                reds[(h2 << 9) + c2] = sB;
            }
            __syncthreads();
            if (t < 512) {
                tmv = reds[t] + reds[512 + t];
                cstore_f2(poutG + (size_t)(((b2i << 4) + stripe) * LL + t) * 2,
                          make_float2(tyv, tmv));
            }
            __builtin_amdgcn_fence(__ATOMIC_RELEASE, "workgroup");
            __syncthreads();
            if (t == 0) set_flag(flg + FLG_POUT + (b2i << 4) + stripe);
        }
    }

    // ===================== Phase D: combine output partials (per batch) ========
    if (t < 16) wait_flag(flg + FLG_POUT + (b2i << 4) + t);
    __syncthreads();
    if (t < 32) {
        int c = (stripe << 5) + t;
        float a = 0.f, d = 0.f;
        #pragma unroll
        for (int s = 0; s < 16; ++s) {
            float2 p = cload_f2(poutG + (size_t)(((b2i << 4) + s) * LL + c) * 2);
            a += p.x; d += p.y;
        }
        out[(b2i << 9) + c] = a;                 // types_permed
        out[BB * LL + (b2i << 9) + c] = d;       // times_permed
    }
}

extern "C" void kernel_launch(void* const* d_in, const int* in_sizes, int n_in,
                              void* d_out, int out_size, void* d_ws, size_t ws_size,
                              hipStream_t stream)
{
    const float* etime = (const float*)d_in[0];
    const int*   etype = (const int*)d_in[1];
    const float* x     = (const float*)d_in[2];
    const int*   slens = (const int*)d_in[3];
    const float* gum   = (const float*)d_in[4];
    const float* W1    = (const float*)d_in[5];
    const float* b1    = (const float*)d_in[6];
    const float* W2    = (const float*)d_in[7];
    const float* b2    = (const float*)d_in[8];
    float* out = (float*)d_out;
    float* wsf = (float*)d_ws;

    // zero all flag words (ws words [0,2048)) deterministically per replay;
    // cpk partials are flag-gated so they need no reset.
    hipMemsetAsync(d_ws, 0, 8192, stream);

    void* args[] = {(void*)&etime, (void*)&etype, (void*)&x, (void*)&slens, (void*)&gum,
                    (void*)&W1, (void*)&b1, (void*)&W2, (void*)&b2, (void*)&out, (void*)&wsf};
    hipError_t err = hipLaunchCooperativeKernel((const void*)mega, dim3(NBLK), dim3(NTHR),
                                                args, 0, stream);
    if (err != hipSuccess) {
        // 256 blocks x 1024 thr, ~76KB LDS -> 1 block/CU on 256 CUs (co-resident;
        // flag deps only ever point at co-resident blocks).
        mega<<<NBLK, NTHR, 0, stream>>>(etime, etype, x, slens, gum, W1, b1, W2, b2, out, wsf);
    }
}